// Round 1
// baseline (2812.946 us; speedup 1.0000x reference)
//
#include <hip/hip_runtime.h>

#define N_B 64
#define T_F 300
#define V_J 25
#define WIN 5
#define VW 125
#define EM 96
#define KD 18

// workspace float offsets
#define OFF_AT 0         // [6][125][125]  AT[s][u][vp] = A_norm_s[vp][u]
#define OFF_WP 93760     // [96][18] folded mlp weight
#define OFF_BP 95488     // [96] folded mlp bias
#define OFF_OB 95584     // [96] folded out bias
#define OFF_OW 95680     // [5][96][96] folded out weight [w][c][o2]

__device__ __constant__ int EDGES[24][2] = {
  {1,2},{2,21},{3,21},{4,3},{5,21},{6,5},{7,6},{8,7},{9,21},{10,9},{11,10},{12,11},
  {13,1},{14,13},{15,14},{16,15},{17,1},{18,17},{19,18},{20,19},{22,23},{23,8},{24,25},{25,12}
};

// Build the 6 normalized k-adjacency scales (125x125 each) on device.
// min((A_large+I)^k,1) is k-hop reachability on the tiled skeleton graph.
__global__ void build_A_kernel(float* __restrict__ ws) {
  __shared__ unsigned int adjJ[32];
  __shared__ unsigned long long adj[125][2];
  __shared__ unsigned long long R[6][125][2];
  __shared__ double dinv[125];
  int tid = threadIdx.x;
  if (tid < 25) {
    unsigned int m = 1u << tid;  // self loop
    for (int e = 0; e < 24; ++e) {
      int a = EDGES[e][0]-1, b = EDGES[e][1]-1;
      if (a == tid) m |= 1u<<b;
      if (b == tid) m |= 1u<<a;
    }
    adjJ[tid] = m;
  }
  __syncthreads();
  if (tid < 125) {
    int ji = tid % 25;
    unsigned long long m0 = 0, m1 = 0;
    for (int j = 0; j < 125; ++j) {
      if ((adjJ[ji] >> (j % 25)) & 1u) {
        if (j < 64) m0 |= 1ull << j; else m1 |= 1ull << (j-64);
      }
    }
    adj[tid][0] = m0; adj[tid][1] = m1;
    R[0][tid][0] = (tid < 64) ? (1ull << tid) : 0ull;
    R[0][tid][1] = (tid >= 64) ? (1ull << (tid-64)) : 0ull;
  }
  __syncthreads();
  for (int k = 1; k <= 5; ++k) {
    if (tid < 125) {
      unsigned long long p0 = R[k-1][tid][0], p1 = R[k-1][tid][1];
      unsigned long long n0 = p0, n1 = p1;
      for (int u = 0; u < 64; ++u)  if ((p0>>u)&1)      { n0 |= adj[u][0]; n1 |= adj[u][1]; }
      for (int u = 64; u < 125; ++u) if ((p1>>(u-64))&1) { n0 |= adj[u][0]; n1 |= adj[u][1]; }
      R[k][tid][0] = n0; R[k][tid][1] = n1;
    }
    __syncthreads();
  }
  for (int s = 0; s < 6; ++s) {
    unsigned long long g0 = 0, g1 = 0;
    if (tid < 125) {
      if (s == 0) {
        g0 = (tid<64)?(1ull<<tid):0ull; g1 = (tid>=64)?(1ull<<(tid-64)):0ull;
      } else {
        g0 = R[s][tid][0] & ~R[s-1][tid][0];
        g1 = R[s][tid][1] & ~R[s-1][tid][1];
        if (tid < 64) g0 |= 1ull<<tid; else g1 |= 1ull<<(tid-64);
      }
      int d = __popcll(g0) + __popcll(g1);
      dinv[tid] = (d > 0) ? 1.0/sqrt((double)d) : 0.0;
    }
    __syncthreads();
    if (tid < 125) {
      double di = dinv[tid];
      for (int j = 0; j < 125; ++j) {
        bool bit = (j<64) ? ((g0>>j)&1ull) : ((g1>>(j-64))&1ull);
        float val = bit ? (float)(di * dinv[j]) : 0.0f;
        // symmetric, so AT[s][u=tid][vp=j] = A_norm[j][tid] = A_norm[tid][j]
        ws[OFF_AT + (s*125 + tid)*125 + j] = val;
      }
    }
    __syncthreads();
  }
}

// Fold BN into weights/biases; transpose out_w to [w][c][o2].
__global__ void fold_kernel(const float* __restrict__ mlp_w, const float* __restrict__ mlp_b,
    const float* __restrict__ g1, const float* __restrict__ be1,
    const float* __restrict__ mu1, const float* __restrict__ va1,
    const float* __restrict__ out_w, const float* __restrict__ out_b,
    const float* __restrict__ g2, const float* __restrict__ be2,
    const float* __restrict__ mu2, const float* __restrict__ va2,
    float* __restrict__ ws) {
  int idx = blockIdx.x * blockDim.x + threadIdx.x;
  if (idx < EM*KD) {
    int o = idx / KD;
    float inv = g1[o] / sqrtf(va1[o] + 1e-5f);
    ws[OFF_WP + idx] = mlp_w[idx] * inv;
  }
  if (idx < EM) {
    float inv = g1[idx] / sqrtf(va1[idx] + 1e-5f);
    ws[OFF_BP + idx] = mlp_b[idx] * inv + be1[idx] - mu1[idx] * inv;
    float inv2 = g2[idx] / sqrtf(va2[idx] + 1e-5f);
    ws[OFF_OB + idx] = out_b[idx] * inv2 + be2[idx] - mu2[idx] * inv2;
  }
  int total = gridDim.x * blockDim.x;
  for (int i = idx; i < WIN*EM*EM; i += total) {
    int wq = i / (EM*EM);
    int r  = i % (EM*EM);
    int o2 = r % EM;
    int c  = r / EM;
    float inv2 = g2[o2] / sqrtf(va2[o2] + 1e-5f);
    ws[OFF_OW + i] = out_w[(o2*EM + c)*WIN + wq] * inv2;
  }
}

#define CHUNK 16
#define NCHUNK 6

// Fully fused main kernel: one block per (n,t).
__global__ __launch_bounds__(256, 2) void msg3d_main(const float* __restrict__ x,
    const float* __restrict__ ws, float* __restrict__ out) {
  __shared__ float xw[3*128];            // xw[c][u], u = w*25+vv
  __shared__ float zb[18*126];           // z[k=(s*3+c)][vp]
  __shared__ float Wp[96*18];
  __shared__ float bp[96];
  __shared__ float ob[96];
  __shared__ float hb[125*(CHUNK+1)];    // h[vp][c_local], pad stride 17
  __shared__ float wsl[5*CHUNK*96];      // out_w slice [w][c_local][o2]

  int blk = blockIdx.x;
  int n = blk / T_F;
  int t = blk % T_F;
  int tid = threadIdx.x;

  for (int i = tid; i < EM*KD; i += 256) Wp[i] = ws[OFF_WP + i];
  if (tid < EM) { bp[tid] = ws[OFF_BP + tid]; ob[tid] = ws[OFF_OB + tid]; }
  for (int i = tid; i < 3*VW; i += 256) {
    int c = i / VW, u = i % VW;
    int w = u / V_J, vv = u % V_J;
    int tt = t + w - 2;
    float val = 0.0f;
    if (tt >= 0 && tt < T_F) val = x[((n*3 + c)*T_F + tt)*V_J + vv];
    xw[c*128 + u] = val;
  }
  __syncthreads();

  // Phase Z: z[(s,c)][vp] = sum_u AT[s][u][vp] * xw[c][u]  (A from L2, 3x reg reuse)
  for (int it = 0; it < 3; ++it) {
    int idx = it*256 + tid;
    if (idx < 750) {
      int s = idx / VW, vp = idx % VW;
      const float* Acol = ws + OFF_AT + (s*VW)*VW + vp;  // stride 125 over u
      float a0 = 0.f, a1 = 0.f, a2 = 0.f;
      for (int u = 0; u < VW; ++u) {
        float a = Acol[u*VW];
        a0 = fmaf(a, xw[u],       a0);
        a1 = fmaf(a, xw[128 + u], a1);
        a2 = fmaf(a, xw[256 + u], a2);
      }
      zb[(s*3+0)*126 + vp] = a0;
      zb[(s*3+1)*126 + vp] = a1;
      zb[(s*3+2)*126 + vp] = a2;
    }
  }
  __syncthreads();

  float acc[2][5];
  #pragma unroll
  for (int a = 0; a < 2; ++a)
    #pragma unroll
    for (int b = 0; b < 5; ++b) acc[a][b] = 0.0f;

  int og = tid / 5, vg = tid % 5;  // valid when tid < 240: o2 = og*2+{0,1}, v = vg*5+{0..4}

  for (int chunk = 0; chunk < NCHUNK; ++chunk) {
    int c0 = chunk * CHUNK;
    // stage out_w slice for this c-chunk (all 5 w)
    for (int i = tid; i < 5*CHUNK*EM; i += 256) {
      int wq = i / (CHUNK*EM);
      int r  = i % (CHUNK*EM);
      wsl[i] = ws[OFF_OW + (wq*EM + c0)*EM + r];
    }
    // Phase H: h[o][vp] for o in [c0, c0+CHUNK), BN+ReLU folded
    for (int i = tid; i < CHUNK*VW; i += 256) {
      int ol = i / VW, vp = i % VW;
      int o = c0 + ol;
      float a = bp[o];
      #pragma unroll
      for (int k = 0; k < KD; ++k) a = fmaf(Wp[o*KD + k], zb[k*126 + vp], a);
      hb[vp*(CHUNK+1) + ol] = fmaxf(a, 0.0f);
    }
    __syncthreads();
    // Phase C: out conv partial over this c-chunk
    if (tid < 240) {
      #pragma unroll
      for (int wq = 0; wq < WIN; ++wq) {
        for (int cl = 0; cl < CHUNK; ++cl) {
          float w0 = wsl[(wq*CHUNK + cl)*EM + og*2 + 0];
          float w1 = wsl[(wq*CHUNK + cl)*EM + og*2 + 1];
          #pragma unroll
          for (int j = 0; j < 5; ++j) {
            float hv = hb[(wq*V_J + vg*5 + j)*(CHUNK+1) + cl];
            acc[0][j] = fmaf(w0, hv, acc[0][j]);
            acc[1][j] = fmaf(w1, hv, acc[1][j]);
          }
        }
      }
    }
    __syncthreads();
  }

  if (tid < 240) {
    #pragma unroll
    for (int jo = 0; jo < 2; ++jo) {
      int o2 = og*2 + jo;
      float obv = ob[o2];
      #pragma unroll
      for (int j = 0; j < 5; ++j) {
        int v = vg*5 + j;
        out[((n*EM + o2)*T_F + t)*V_J + v] = acc[jo][j] + obv;
      }
    }
  }
}

extern "C" void kernel_launch(void* const* d_in, const int* in_sizes, int n_in,
                              void* d_out, int out_size, void* d_ws, size_t ws_size,
                              hipStream_t stream) {
  const float* x     = (const float*)d_in[0];
  const float* mlp_w = (const float*)d_in[1];
  const float* mlp_b = (const float*)d_in[2];
  const float* g1    = (const float*)d_in[3];
  const float* be1   = (const float*)d_in[4];
  const float* mu1   = (const float*)d_in[5];
  const float* va1   = (const float*)d_in[6];
  const float* out_w = (const float*)d_in[7];
  const float* out_b = (const float*)d_in[8];
  const float* g2    = (const float*)d_in[9];
  const float* be2   = (const float*)d_in[10];
  const float* mu2   = (const float*)d_in[11];
  const float* va2   = (const float*)d_in[12];
  float* out = (float*)d_out;
  float* ws  = (float*)d_ws;

  build_A_kernel<<<1, 128, 0, stream>>>(ws);
  fold_kernel<<<180, 256, 0, stream>>>(mlp_w, mlp_b, g1, be1, mu1, va1,
                                       out_w, out_b, g2, be2, mu2, va2, ws);
  msg3d_main<<<N_B * T_F, 256, 0, stream>>>(x, ws, out);
}

// Round 2
// 657.090 us; speedup vs baseline: 4.2809x; 4.2809x over previous
//
#include <hip/hip_runtime.h>

typedef __attribute__((ext_vector_type(8))) _Float16 f16x8;
typedef __attribute__((ext_vector_type(4))) _Float16 f16x4;
typedef __attribute__((ext_vector_type(4))) float f32x4;

#define N_B 64
#define T_F 300
#define TB 4
#define NT (T_F/TB)

// ws byte offsets
#define ABF_OFF 0                   // _Float16 [6][128][128]  (196608 B)
#define WH_OFF  196608              // _Float16 [96][32]       (6144 B)
#define OWC_OFF 202752              // _Float16 [6][96][96]    (110592 B)
#define BP_OFF  313344              // float [96]
#define OB_OFF  313728              // float [96]

__device__ __constant__ int EDGES[24][2] = {
  {1,2},{2,21},{3,21},{4,3},{5,21},{6,5},{7,6},{8,7},{9,21},{10,9},{11,10},{12,11},
  {13,1},{14,13},{15,14},{16,15},{17,1},{18,17},{19,18},{20,19},{22,23},{23,8},{24,25},{25,12}
};

// Build 6 normalized k-adjacency scales as f16 [6][128][128], zero-padded.
__global__ void build_A_kernel(char* __restrict__ wsb) {
  _Float16* Abf = (_Float16*)(wsb + ABF_OFF);
  __shared__ unsigned int adjJ[32];
  __shared__ unsigned long long adj[125][2];
  __shared__ unsigned long long R[6][125][2];
  __shared__ double dinv[125];
  int tid = threadIdx.x;
  if (tid < 25) {
    unsigned int m = 1u << tid;
    for (int e = 0; e < 24; ++e) {
      int a = EDGES[e][0]-1, b = EDGES[e][1]-1;
      if (a == tid) m |= 1u<<b;
      if (b == tid) m |= 1u<<a;
    }
    adjJ[tid] = m;
  }
  __syncthreads();
  if (tid < 125) {
    int ji = tid % 25;
    unsigned long long m0 = 0, m1 = 0;
    for (int j = 0; j < 125; ++j) {
      if ((adjJ[ji] >> (j % 25)) & 1u) {
        if (j < 64) m0 |= 1ull << j; else m1 |= 1ull << (j-64);
      }
    }
    adj[tid][0] = m0; adj[tid][1] = m1;
    R[0][tid][0] = (tid < 64) ? (1ull << tid) : 0ull;
    R[0][tid][1] = (tid >= 64) ? (1ull << (tid-64)) : 0ull;
  }
  __syncthreads();
  for (int k = 1; k <= 5; ++k) {
    if (tid < 125) {
      unsigned long long p0 = R[k-1][tid][0], p1 = R[k-1][tid][1];
      unsigned long long n0 = p0, n1 = p1;
      for (int u = 0; u < 64; ++u)   if ((p0>>u)&1)      { n0 |= adj[u][0]; n1 |= adj[u][1]; }
      for (int u = 64; u < 125; ++u) if ((p1>>(u-64))&1) { n0 |= adj[u][0]; n1 |= adj[u][1]; }
      R[k][tid][0] = n0; R[k][tid][1] = n1;
    }
    __syncthreads();
  }
  for (int s = 0; s < 6; ++s) {
    unsigned long long g0 = 0, g1 = 0;
    if (tid < 125) {
      if (s == 0) {
        g0 = (tid<64)?(1ull<<tid):0ull; g1 = (tid>=64)?(1ull<<(tid-64)):0ull;
      } else {
        g0 = R[s][tid][0] & ~R[s-1][tid][0];
        g1 = R[s][tid][1] & ~R[s-1][tid][1];
        if (tid < 64) g0 |= 1ull<<tid; else g1 |= 1ull<<(tid-64);
      }
      int d = __popcll(g0) + __popcll(g1);
      dinv[tid] = (d > 0) ? 1.0/sqrt((double)d) : 0.0;
    }
    __syncthreads();
    if (tid < 128) {
      double di = (tid < 125) ? dinv[tid] : 0.0;
      for (int j = 0; j < 128; ++j) {
        float val = 0.0f;
        if (tid < 125 && j < 125) {
          bool bit = (j<64) ? ((g0>>j)&1ull) : ((g1>>(j-64))&1ull);
          if (bit) val = (float)(di * dinv[j]);
        }
        Abf[(s*128 + tid)*128 + j] = (_Float16)val;  // symmetric matrix
      }
    }
    __syncthreads();
  }
}

// Fold BN into weights, convert to f16, consumer-friendly layouts.
__global__ void fold_kernel(const float* __restrict__ mlp_w, const float* __restrict__ mlp_b,
    const float* __restrict__ g1, const float* __restrict__ be1,
    const float* __restrict__ mu1, const float* __restrict__ va1,
    const float* __restrict__ out_w, const float* __restrict__ out_b,
    const float* __restrict__ g2, const float* __restrict__ be2,
    const float* __restrict__ mu2, const float* __restrict__ va2,
    char* __restrict__ wsb) {
  _Float16* Wh = (_Float16*)(wsb + WH_OFF);
  _Float16* OW = (_Float16*)(wsb + OWC_OFF);
  float* bp = (float*)(wsb + BP_OFF);
  float* ob = (float*)(wsb + OB_OFF);
  int idx = blockIdx.x*blockDim.x + threadIdx.x;
  int total = gridDim.x*blockDim.x;
  for (int i = idx; i < 96*32; i += total) {
    int o = i >> 5, k = i & 31;
    float inv = g1[o] / sqrtf(va1[o] + 1e-5f);
    Wh[i] = (_Float16)((k < 18) ? mlp_w[o*18 + k] * inv : 0.0f);
  }
  for (int i = idx; i < 6*96*96; i += total) {
    int ch = i / (96*96);
    int r  = i % (96*96);
    int o2 = r / 96;
    int k2 = r % 96;            // k2 = wq*16 + cl
    float val = 0.0f;
    if (k2 < 80) {
      int wq = k2 >> 4, cl = k2 & 15;
      int c = ch*16 + cl;
      float inv2 = g2[o2] / sqrtf(va2[o2] + 1e-5f);
      val = out_w[(o2*96 + c)*5 + wq] * inv2;
    }
    OW[i] = (_Float16)val;
  }
  for (int i = idx; i < 96; i += total) {
    float inv = g1[i] / sqrtf(va1[i] + 1e-5f);
    bp[i] = mlp_b[i]*inv + be1[i] - mu1[i]*inv;
    float inv2 = g2[i] / sqrtf(va2[i] + 1e-5f);
    ob[i] = out_b[i]*inv2 + be2[i] - mu2[i]*inv2;
  }
}

// Fused Z->H->C, all three phases on MFMA f16. Block = (n, 4 t's), 256 thr.
__global__ __launch_bounds__(256, 2) void msg3d_main(const float* __restrict__ x,
    const char* __restrict__ ws, float* __restrict__ out) {
  __shared__ __align__(16) char smem[75776];
  _Float16* zB  = (_Float16*)smem;                    // [512][32]  cols (tl*128+wv), k=s*3+c
  _Float16* AsL = (_Float16*)(smem + 32768);          // [128][136] P1 only
  _Float16* xwB = (_Float16*)(smem + 32768 + 34816);  // [16][136]  P1 only
  _Float16* hB  = (_Float16*)(smem + 32768);          // [128][96]  P2/P3
  _Float16* OWL = (_Float16*)(smem + 32768 + 24576);  // [96][96]   P2/P3

  const int tid = threadIdx.x;
  const int wid = tid >> 6, lane = tid & 63, quad = lane >> 4, l16 = lane & 15;
  const int blk = blockIdx.x;
  const int n = blk / NT, t0 = (blk % NT) * TB;
  const _Float16* Abf = (const _Float16*)(ws + ABF_OFF);
  const _Float16* WhG = (const _Float16*)(ws + WH_OFF);
  const _Float16* OWG = (const _Float16*)(ws + OWC_OFF);
  const float* bpG = (const float*)(ws + BP_OFF);
  const float* obG = (const float*)(ws + OB_OFF);
  const f32x4 fzero = {0.f, 0.f, 0.f, 0.f};

  // P0: zero zB (k-pad 18..31 must be 0), build xwB (B-operand of Z GEMM)
  for (int i = tid; i < 2048; i += 256) *(f32x4*)(zB + i*8) = fzero;
  for (int i = tid; i < 2048; i += 256) {
    int col = i >> 7, u = i & 127;
    float val = 0.0f;
    if (col < 12 && u < 125) {
      int c = col >> 2, tl = col & 3;
      int w = u / 25, v = u - w*25;
      int fr = t0 + tl + w - 2;
      if (fr >= 0 && fr < T_F) val = x[((n*3 + c)*T_F + fr)*25 + v];
    }
    xwB[col*136 + u] = (_Float16)val;
  }
  __syncthreads();

  // P1: Z = A_s @ XW  (M=128/s, K=128, N=16; wave owns 2 mtiles)
  for (int s = 0; s < 6; ++s) {
    for (int it = 0; it < 8; ++it) {
      int f = (it*256 + tid) * 8;
      int u = f >> 7, wv0 = f & 127;
      f32x4 d = *(const f32x4*)(Abf + s*16384 + f);
      *(f32x4*)(AsL + u*136 + wv0) = d;
    }
    __syncthreads();
    f32x4 z0 = fzero, z1 = fzero;
    const int m0 = wid * 2;
    #pragma unroll
    for (int kt = 0; kt < 4; ++kt) {
      f16x8 b  = *(f16x8*)(xwB + l16*136 + kt*32 + quad*8);
      f16x8 a0 = *(f16x8*)(AsL + (m0*16 + l16)*136 + kt*32 + quad*8);
      f16x8 a1 = *(f16x8*)(AsL + (m0*16 + 16 + l16)*136 + kt*32 + quad*8);
      z0 = __builtin_amdgcn_mfma_f32_16x16x32_f16(a0, b, z0, 0, 0, 0);
      z1 = __builtin_amdgcn_mfma_f32_16x16x32_f16(a1, b, z1, 0, 0, 0);
    }
    if (l16 < 12) {
      int c = l16 >> 2, tl = l16 & 3;
      int kz = s*3 + c;
      #pragma unroll
      for (int r = 0; r < 4; ++r) {
        int wv = m0*16 + quad*4 + r;
        zB[(tl*128 + wv)*32 + kz]      = (_Float16)z0[r];
        zB[(tl*128 + wv + 16)*32 + kz] = (_Float16)z1[r];
      }
    }
    __syncthreads();
  }

  // hB pad safety: zero all of hB once (k2 80..95 and cols 100..127 stay 0)
  for (int i = tid; i < 1536; i += 256) *(f32x4*)(hB + i*8) = fzero;

  f32x4 cacc[6][2];
  #pragma unroll
  for (int m = 0; m < 6; ++m) { cacc[m][0] = fzero; cacc[m][1] = fzero; }

  // P2+P3: per c-chunk of 16: H = Wh_chunk @ zB (bias+ReLU) -> hB; C += OW_chunk @ hB
  for (int ch = 0; ch < 6; ++ch) {
    for (int it = 0; it < 5; ++it) {
      int idx = it*256 + tid;
      if (idx < 1152) {
        int f = idx * 8;
        f32x4 d = *(const f32x4*)(OWG + ch*9216 + f);
        *(f32x4*)(OWL + f) = d;   // same flat layout as global
      }
    }
    f16x8 wa = *(const f16x8*)(WhG + (ch*16 + l16)*32 + quad*8);
    float bpv[4];
    #pragma unroll
    for (int r = 0; r < 4; ++r) bpv[r] = bpG[ch*16 + quad*4 + r];
    __syncthreads();

    #pragma unroll
    for (int nt8 = 0; nt8 < 8; ++nt8) {
      int nt = wid*8 + nt8;
      f16x8 zb = *(f16x8*)(zB + (nt*16 + l16)*32 + quad*8);
      f32x4 hc = __builtin_amdgcn_mfma_f32_16x16x32_f16(wa, zb, fzero, 0, 0, 0);
      int col = nt*16 + l16;
      int tl = col >> 7, wv = col & 127;
      if (wv < 125) {
        int wq = wv / 25, v = wv - wq*25;
        int col2 = tl*25 + v;
        f16x4 hv;
        #pragma unroll
        for (int r = 0; r < 4; ++r) {
          float h = hc[r] + bpv[r];
          hv[r] = (_Float16)(h > 0.0f ? h : 0.0f);
        }
        *(f16x4*)(hB + col2*96 + wq*16 + quad*4) = hv;
      }
    }
    __syncthreads();

    #pragma unroll
    for (int kt = 0; kt < 3; ++kt) {
      f16x8 b0 = *(f16x8*)(hB + ((wid*2    )*16 + l16)*96 + kt*32 + quad*8);
      f16x8 b1 = *(f16x8*)(hB + ((wid*2 + 1)*16 + l16)*96 + kt*32 + quad*8);
      #pragma unroll
      for (int m = 0; m < 6; ++m) {
        f16x8 a = *(f16x8*)(OWL + (m*16 + l16)*96 + kt*32 + quad*8);
        cacc[m][0] = __builtin_amdgcn_mfma_f32_16x16x32_f16(a, b0, cacc[m][0], 0, 0, 0);
        cacc[m][1] = __builtin_amdgcn_mfma_f32_16x16x32_f16(a, b1, cacc[m][1], 0, 0, 0);
      }
    }
    __syncthreads();
  }

  // Epilogue: C-frags -> out, + folded out bias
  #pragma unroll
  for (int nn = 0; nn < 2; ++nn) {
    int col2 = (wid*2 + nn)*16 + l16;
    if (col2 < 100) {
      int tl = col2 / 25, v = col2 - tl*25;
      #pragma unroll
      for (int m = 0; m < 6; ++m) {
        #pragma unroll
        for (int r = 0; r < 4; ++r) {
          int o2 = m*16 + quad*4 + r;
          out[((n*96 + o2)*T_F + t0 + tl)*25 + v] = cacc[m][nn][r] + obG[o2];
        }
      }
    }
  }
}

extern "C" void kernel_launch(void* const* d_in, const int* in_sizes, int n_in,
                              void* d_out, int out_size, void* d_ws, size_t ws_size,
                              hipStream_t stream) {
  const float* x     = (const float*)d_in[0];
  const float* mlp_w = (const float*)d_in[1];
  const float* mlp_b = (const float*)d_in[2];
  const float* g1    = (const float*)d_in[3];
  const float* be1   = (const float*)d_in[4];
  const float* mu1   = (const float*)d_in[5];
  const float* va1   = (const float*)d_in[6];
  const float* out_w = (const float*)d_in[7];
  const float* out_b = (const float*)d_in[8];
  const float* g2    = (const float*)d_in[9];
  const float* be2   = (const float*)d_in[10];
  const float* mu2   = (const float*)d_in[11];
  const float* va2   = (const float*)d_in[12];
  float* out = (float*)d_out;
  char*  ws  = (char*)d_ws;

  build_A_kernel<<<1, 128, 0, stream>>>(ws);
  fold_kernel<<<64, 256, 0, stream>>>(mlp_w, mlp_b, g1, be1, mu1, va1,
                                      out_w, out_b, g2, be2, mu2, va2, ws);
  msg3d_main<<<N_B * NT, 256, 0, stream>>>(x, ws, out);
}

// Round 3
// 411.700 us; speedup vs baseline: 6.8325x; 1.5960x over previous
//
#include <hip/hip_runtime.h>

typedef __attribute__((ext_vector_type(8))) _Float16 f16x8;
typedef __attribute__((ext_vector_type(4))) _Float16 f16x4;
typedef __attribute__((ext_vector_type(4))) float f32x4;

#define N_B 64
#define T_F 300
#define TB 4
#define NT (T_F/TB)

// ws byte offsets
#define AY_OFF  0        // f16 [4][128][8]   y-GEMM A operand, chunked
#define WH_OFF  8192     // f16 [96][32]      folded mlp weight
#define OWC_OFF 14336    // f16 [6][12][96][8] folded out weight, chunked
#define BP_OFF  124928   // float[96]
#define OB_OFF  125312   // float[96]
#define DSQ_OFF 125696   // float[6][32]      alpha_s(v) = dinv_s(v)^2 (s>=2), 0 for s<2

__device__ __constant__ int EDGES[24][2] = {
  {1,2},{2,21},{3,21},{4,3},{5,21},{6,5},{7,6},{8,7},{9,21},{10,9},{11,10},{12,11},
  {13,1},{14,13},{15,14},{16,15},{17,1},{18,17},{19,18},{20,19},{22,23},{23,8},{24,25},{25,12}
};

// One setup kernel: block 0 does the 25-node BFS + Ay/dsq; all blocks fold BN weights.
__global__ void setup_kernel(const float* __restrict__ mlp_w, const float* __restrict__ mlp_b,
    const float* __restrict__ g1, const float* __restrict__ be1,
    const float* __restrict__ mu1, const float* __restrict__ va1,
    const float* __restrict__ out_w, const float* __restrict__ out_b,
    const float* __restrict__ g2, const float* __restrict__ be2,
    const float* __restrict__ mu2, const float* __restrict__ va2,
    char* __restrict__ wsb) {
  _Float16* Ay  = (_Float16*)(wsb + AY_OFF);
  _Float16* Wh  = (_Float16*)(wsb + WH_OFF);
  _Float16* OWc = (_Float16*)(wsb + OWC_OFF);
  float* bp  = (float*)(wsb + BP_OFF);
  float* ob  = (float*)(wsb + OB_OFF);
  float* dsq = (float*)(wsb + DSQ_OFF);
  int tid = threadIdx.x;

  if (blockIdx.x == 0) {
    // A_large = J5 (x) B with B = A+I  =>  scale s reduces to 25-node graph:
    //   s=0: A_s = I;  s=1: M = J(x)B;  s>=2: M = J(x)(R_s\R_{s-1}) + I.
    __shared__ unsigned int Rk[6][25];
    __shared__ unsigned int Gs[6][25];
    __shared__ float dv[6][25];
    if (tid < 25) {
      unsigned int m = 1u << tid;
      for (int e = 0; e < 24; ++e) {
        int a = EDGES[e][0]-1, b = EDGES[e][1]-1;
        if (a == tid) m |= 1u<<b;
        if (b == tid) m |= 1u<<a;
      }
      Gs[1][tid] = m;   // B masks (incl. self)
      Rk[1][tid] = m;
    }
    __syncthreads();
    for (int k = 2; k <= 5; ++k) {
      if (tid < 25) {
        unsigned int p = Rk[k-1][tid], nm = p;
        for (int j = 0; j < 25; ++j) if ((p>>j)&1u) nm |= Gs[1][j];
        Rk[k][tid] = nm;
      }
      __syncthreads();
    }
    if (tid < 25) {
      for (int s = 1; s <= 5; ++s) {
        unsigned int g = (s==1) ? Gs[1][tid] : (Rk[s][tid] & ~Rk[s-1][tid]);
        if (s >= 2) Gs[s][tid] = g;
        int d = 5*__popc(g) + ((s>=2)?1:0);
        dv[s][tid] = (d>0) ? (float)(1.0/sqrt((double)d)) : 0.0f;
      }
    }
    __syncthreads();
    for (int i = tid; i < 6*32; i += 256) {
      int s = i>>5, v = i&31;
      float val = 0.f;
      if (s >= 2 && v < 25) { float t = dv[s][v]; val = t*t; }
      dsq[i] = val;
    }
    for (int idx = tid; idx < 4096; idx += 256) {
      int kc = idx >> 10, row = (idx>>3)&127, j = idx&7;
      int i = kc*8 + j;
      float val = 0.f;
      if (row < 125 && i < 25) {
        int s = 1 + row/25, v = row - (s-1)*25;
        if ((Gs[s][v] >> i) & 1u) val = dv[s][v]*dv[s][i];
      }
      Ay[idx] = (_Float16)val;
    }
  }

  int gidx = blockIdx.x*256 + tid;
  int total = gridDim.x*256;
  for (int i = gidx; i < 96*32; i += total) {
    int o = i>>5, k = i&31;
    float inv = g1[o] / sqrtf(va1[o] + 1e-5f);
    Wh[i] = (_Float16)((k < 18) ? mlp_w[o*18 + k]*inv : 0.0f);
  }
  for (int i = gidx; i < 6*12*96*8; i += total) {
    int ch = i / 9216;
    int r  = i % 9216;
    int kc = r / 768;
    int r2 = r % 768;
    int m16 = r2 >> 3, j = r2 & 7;
    int k2 = kc*8 + j;            // k2 = wq*16 + cl
    float val = 0.f;
    if (k2 < 80) {
      int wq = k2 >> 4, cl = k2 & 15;
      int c = ch*16 + cl;
      float inv2 = g2[m16] / sqrtf(va2[m16] + 1e-5f);
      val = out_w[(m16*96 + c)*5 + wq] * inv2;
    }
    OWc[i] = (_Float16)val;
  }
  for (int i = gidx; i < 96; i += total) {
    float inv = g1[i] / sqrtf(va1[i] + 1e-5f);
    bp[i] = mlp_b[i]*inv + be1[i] - mu1[i]*inv;
    float inv2 = g2[i] / sqrtf(va2[i] + 1e-5f);
    ob[i] = out_b[i]*inv2 + be2[i] - mu2[i]*inv2;
  }
}

// LDS layout (bytes)
#define ZB_OFF 0        // f16 [3][512][8]   z chunks kc=0..2 (quad=3 reads zero strip)
#define HB_OFF 24576    // f16 [10][128][8]  h chunks kc=0..9 (kc>=10 reads zero strip)
#define XW_OFF 45056    // f16 [16][136]     xw[col=(c*4+tl)][u=w*25+v]
#define XS_OFF 49408    // f16 [16][40]      xs[col][i] window sums
#define ZP_OFF 50688    // f16 zero strip (16 B)
#define SM_BYTES 50704

__global__ __launch_bounds__(256, 3) void msg3d_main(const float* __restrict__ x,
    const char* __restrict__ ws, float* __restrict__ out) {
  __shared__ __align__(16) char smem[SM_BYTES];
  _Float16* zB = (_Float16*)(smem + ZB_OFF);
  _Float16* hB = (_Float16*)(smem + HB_OFF);
  _Float16* xw = (_Float16*)(smem + XW_OFF);
  _Float16* xs = (_Float16*)(smem + XS_OFF);
  _Float16* zp = (_Float16*)(smem + ZP_OFF);

  const int tid = threadIdx.x;
  const int wid = tid>>6, lane = tid&63, quad = lane>>4, l16 = lane&15;
  const int n = blockIdx.x / NT, t0 = (blockIdx.x % NT)*TB;
  const _Float16* AyG = (const _Float16*)(ws + AY_OFF);
  const _Float16* WhG = (const _Float16*)(ws + WH_OFF);
  const _Float16* OWG = (const _Float16*)(ws + OWC_OFF);
  const float* bpG  = (const float*)(ws + BP_OFF);
  const float* obG  = (const float*)(ws + OB_OFF);
  const float* dsqG = (const float*)(ws + DSQ_OFF);
  const f32x4 fzero = {0.f,0.f,0.f,0.f};

  // P0: stage xw; zero zB chunk 2 and the zero strip
  for (int i = tid; i < 2048; i += 256) {
    int col = i>>7, u = i&127;
    float val = 0.f;
    if (col < 12 && u < 125) {
      int c = col>>2, tl = col&3;
      int w = u/25, v = u - w*25;
      int fr = t0 + tl + w - 2;
      if (fr >= 0 && fr < T_F) val = x[((n*3+c)*T_F + fr)*25 + v];
    }
    xw[col*136 + u] = (_Float16)val;
  }
  for (int i = tid; i < 512; i += 256) *(f32x4*)(zB + 8192 + i*8) = fzero;
  if (tid == 0) *(f32x4*)zp = fzero;
  __syncthreads();

  // xs[col][i] = sum_w xw[col][w*25+i]  (f32 accumulate, f16 store; pad k 25..31 = 0)
  for (int i = tid; i < 512; i += 256) {
    int col = i>>5, k = i&31;
    float val = 0.f;
    if (k < 25) {
      float a = 0.f;
      #pragma unroll
      for (int w = 0; w < 5; ++w) a += (float)xw[col*136 + w*25 + k];
      val = a;
    }
    xs[col*40 + k] = (_Float16)val;
  }
  __syncthreads();

  // y-GEMM: D[(s,v)][(c,tl)] = sum_i Ay[m][i] * xs[n][i]   (M=128, N=16, K=32; 2 MFMA/wave)
  const int m0 = wid*2;
  {
    f16x8 bx = *(f16x8*)(xs + l16*40 + quad*8);
    f16x8 a0 = *(const f16x8*)(AyG + (quad*128 + m0*16 + l16)*8);
    f16x8 a1 = *(const f16x8*)(AyG + (quad*128 + m0*16 + 16 + l16)*8);
    f32x4 y0 = __builtin_amdgcn_mfma_f32_16x16x32_f16(a0, bx, fzero, 0, 0, 0);
    f32x4 y1 = __builtin_amdgcn_mfma_f32_16x16x32_f16(a1, bx, fzero, 0, 0, 0);

    // z-epilogue: z[kz=(s,c)][tl*128 + w*25+v] = y + alpha_s(v)*xw[c,tl][w*25+v]
    if (l16 < 12) {
      int c = l16>>2, tl = l16&3;
      #pragma unroll
      for (int half = 0; half < 2; ++half) {
        f32x4 zz = half ? y1 : y0;
        int mt = m0 + half;
        #pragma unroll
        for (int r = 0; r < 4; ++r) {
          int m = mt*16 + quad*4 + r;
          if (m < 125) {
            int s = 1 + m/25;
            int v = m - (s-1)*25;
            float al = dsqG[s*32 + v];
            int kz = s*3 + c;
            int kc = kz>>3, jz = kz&7;
            float yv = zz[r];
            #pragma unroll
            for (int w = 0; w < 5; ++w) {
              float xv = (float)xw[l16*136 + w*25 + v];
              zB[(kc*512 + tl*128 + w*25 + v)*8 + jz] = (_Float16)(yv + al*xv);
            }
          }
        }
      }
    }
  }
  // s=0 rows: z[c][col] = xw[c,tl][u]  (A_0 = I)
  for (int i = tid; i < 1536; i += 256) {
    int c = i>>9, col = i&511;
    int tl = col>>7, u = col&127;
    zB[col*8 + c] = xw[(c*4+tl)*136 + u];
  }
  __syncthreads();

  f32x4 cacc[6][2];
  #pragma unroll
  for (int m = 0; m < 6; ++m) { cacc[m][0] = fzero; cacc[m][1] = fzero; }

  // Per c-chunk: P2 H = Wh @ z (bias+ReLU) -> hB;  P3 C += OW @ hB
  for (int ch = 0; ch < 6; ++ch) {
    f16x8 wa = *(const f16x8*)(WhG + (ch*16 + l16)*32 + quad*8);
    float bpv[4];
    #pragma unroll
    for (int r = 0; r < 4; ++r) bpv[r] = bpG[ch*16 + quad*4 + r];

    #pragma unroll
    for (int nt8 = 0; nt8 < 8; ++nt8) {
      int nt = wid*8 + nt8;
      int col = nt*16 + l16;
      const _Float16* zsrc = (quad < 3) ? (zB + (quad*512 + col)*8) : zp;
      f16x8 zb = *(f16x8*)zsrc;
      f32x4 hc = __builtin_amdgcn_mfma_f32_16x16x32_f16(wa, zb, fzero, 0, 0, 0);
      int tl = col>>7, wv = col&127;
      if (wv < 125) {
        int wq = wv/25, v = wv - wq*25;
        int col2 = tl*25 + v;
        int k2b = wq*16 + quad*4;
        int kc = k2b>>3, j0 = k2b&7;
        f16x4 hv;
        #pragma unroll
        for (int r = 0; r < 4; ++r) {
          float h = hc[r] + bpv[r];
          hv[r] = (_Float16)(h > 0.0f ? h : 0.0f);
        }
        *(f16x4*)(hB + (kc*128 + col2)*8 + j0) = hv;
      }
    }
    __syncthreads();

    #pragma unroll
    for (int kt = 0; kt < 3; ++kt) {
      int kc = kt*4 + quad;
      int col0 = wid*32 + l16;
      const _Float16* h0 = (kc < 10) ? (hB + (kc*128 + col0)*8)      : zp;
      const _Float16* h1 = (kc < 10) ? (hB + (kc*128 + col0 + 16)*8) : zp;
      f16x8 b0 = *(f16x8*)h0;
      f16x8 b1 = *(f16x8*)h1;
      #pragma unroll
      for (int m = 0; m < 6; ++m) {
        f16x8 a = *(const f16x8*)(OWG + ((ch*12 + kc)*96 + m*16 + l16)*8);
        cacc[m][0] = __builtin_amdgcn_mfma_f32_16x16x32_f16(a, b0, cacc[m][0], 0, 0, 0);
        cacc[m][1] = __builtin_amdgcn_mfma_f32_16x16x32_f16(a, b1, cacc[m][1], 0, 0, 0);
      }
    }
    __syncthreads();
  }

  // Epilogue
  #pragma unroll
  for (int nn = 0; nn < 2; ++nn) {
    int col2 = (wid*2 + nn)*16 + l16;
    if (col2 < 100) {
      int tl = col2 / 25, v = col2 - tl*25;
      #pragma unroll
      for (int m = 0; m < 6; ++m) {
        #pragma unroll
        for (int r = 0; r < 4; ++r) {
          int o2 = m*16 + quad*4 + r;
          out[((n*96 + o2)*T_F + t0 + tl)*25 + v] = cacc[m][nn][r] + obG[o2];
        }
      }
    }
  }
}

extern "C" void kernel_launch(void* const* d_in, const int* in_sizes, int n_in,
                              void* d_out, int out_size, void* d_ws, size_t ws_size,
                              hipStream_t stream) {
  const float* x     = (const float*)d_in[0];
  const float* mlp_w = (const float*)d_in[1];
  const float* mlp_b = (const float*)d_in[2];
  const float* g1    = (const float*)d_in[3];
  const float* be1   = (const float*)d_in[4];
  const float* mu1   = (const float*)d_in[5];
  const float* va1   = (const float*)d_in[6];
  const float* out_w = (const float*)d_in[7];
  const float* out_b = (const float*)d_in[8];
  const float* g2    = (const float*)d_in[9];
  const float* be2   = (const float*)d_in[10];
  const float* mu2   = (const float*)d_in[11];
  const float* va2   = (const float*)d_in[12];
  float* out = (float*)d_out;
  char*  ws  = (char*)d_ws;

  setup_kernel<<<64, 256, 0, stream>>>(mlp_w, mlp_b, g1, be1, mu1, va1,
                                       out_w, out_b, g2, be2, mu2, va2, ws);
  msg3d_main<<<N_B * NT, 256, 0, stream>>>(x, ws, out);
}